// Round 15
// 433.940 us; speedup vs baseline: 1.6208x; 1.0357x over previous
//
#include <hip/hip_runtime.h>
#include <hip/hip_bf16.h>
#include <math.h>

#define NRES 1536
#define NH 16
#define NNF 2359296ull    // NRES*NRES
#define LOG2E 1.44269504f
#define KVS 4             // split-KV ways
#define LDQ 4224          // merged projection C leading dim
#define NTPJ 19           // transpose jobs
#define PROBLK 16914      // prologue block count inside prep_kernel

typedef unsigned short u16;
typedef __attribute__((ext_vector_type(8))) short short8;
typedef __attribute__((ext_vector_type(4))) unsigned short u16x4;
typedef __attribute__((ext_vector_type(4))) float f32x4;

typedef const __attribute__((address_space(1))) void gvoid;
typedef __attribute__((address_space(3))) void lvoid;

__device__ __forceinline__ u16 f2b(float x){
    __hip_bfloat16 h = __float2bfloat16(x);
    return *reinterpret_cast<u16*>(&h);
}
__device__ __forceinline__ float b2f(u16 u){
    unsigned v = ((unsigned)u) << 16;
    return __uint_as_float(v);
}

// ===================== bf16 MFMA GEMM (dbuf, 1 barrier/K-step, XCD swizzle) ==========
#define F_BIAS  1
#define F_SILU  2
#define F_RESID 8
#define F_OUTBF 16

template<int TNF>
__global__ __launch_bounds__(256) void gemm_t(
    const u16* __restrict__ A, int lda, size_t zsA,
    const u16* __restrict__ BT, int ldb, size_t zsB,
    float* __restrict__ Cf, u16* __restrict__ Cb, int ldc, size_t zsC,
    const float* __restrict__ bias, size_t zsBias,
    const float* __restrict__ resid, int ldr, size_t zsR,
    int Ncols, int Kd, int flags, int ksl)
{
    constexpr int TN = TNF * 32;
    __shared__ u16 As[2][128 * 64];
    __shared__ u16 Bs[2][TN * 64];

    unsigned gx = gridDim.x, gy = gridDim.y;
    unsigned nb = gx * gy * gridDim.z;
    unsigned bid = (blockIdx.z * gy + blockIdx.y) * gx + blockIdx.x;
    if ((nb & 7u) == 0u) bid = (bid & 7u) * (nb >> 3) + (bid >> 3);
    const int bxi = bid % gx;
    const int byi = (bid / gx) % gy;
    const int bz  = bid / (gx * gy);

    const int tid = threadIdx.x;
    const int l = tid & 63, w = tid >> 6;
    const int bm = byi * 128, bn = bxi * TN;

    A  += zsA * bz;
    BT += zsB * bz;

    const int kbeg = ksl ? bz * ksl : 0;
    const int kend = ksl ? kbeg + ksl : Kd;
    const int nk = (kend - kbeg) >> 6;

    const int arow   = l >> 3;
    const int aslot  = l & 7;
    const int srcslt = aslot ^ arow;

    const u16* aBase[4];
    const u16* bBase[TN / 32];
    #pragma unroll
    for (int t = 0; t < 4; ++t) {
        int ra = bm + (w * 4 + t) * 8 + arow;
        aBase[t] = A + (size_t)ra * lda + srcslt * 8;
    }
    #pragma unroll
    for (int t = 0; t < TN / 32; ++t) {
        int rb = bn + (w * (TN / 32) + t) * 8 + arow;
        if (rb > Ncols - 1) rb = Ncols - 1;
        bBase[t] = BT + (size_t)rb * ldb + srcslt * 8;
    }

    const int wr = w >> 1, wc = w & 1;
    const int fr = l & 15;
    const int fq = l >> 4;

    f32x4 acc[4][TNF];
    #pragma unroll
    for (int i = 0; i < 4; ++i)
        #pragma unroll
        for (int j = 0; j < TNF; ++j) acc[i][j] = (f32x4){0.f, 0.f, 0.f, 0.f};

    auto stage = [&](int buf, int k0) {
        #pragma unroll
        for (int t = 0; t < 4; ++t)
            __builtin_amdgcn_global_load_lds((gvoid*)(aBase[t] + k0),
                (lvoid*)((char*)As[buf] + (w * 4 + t) * 1024), 16, 0, 0);
        #pragma unroll
        for (int t = 0; t < TN / 32; ++t)
            __builtin_amdgcn_global_load_lds((gvoid*)(bBase[t] + k0),
                (lvoid*)((char*)Bs[buf] + (w * (TN / 32) + t) * 1024), 16, 0, 0);
    };

    stage(0, kbeg);
    __syncthreads();
    int cur = 0;

    for (int it = 0; it < nk; ++it) {
        if (it + 1 < nk) stage(cur ^ 1, kbeg + (it + 1) * 64);
        #pragma unroll
        for (int kk = 0; kk < 2; ++kk) {
            const int slotR = ((kk * 4) + fq) ^ (l & 7);
            short8 av[4], bv[TNF];
            #pragma unroll
            for (int m = 0; m < 4; ++m) {
                int r = wr * 64 + m * 16 + fr;
                av[m] = *(const short8*)((const char*)As[cur] + r * 128 + slotR * 16);
            }
            #pragma unroll
            for (int n = 0; n < TNF; ++n) {
                int r = wc * (TNF * 16) + n * 16 + fr;
                bv[n] = *(const short8*)((const char*)Bs[cur] + r * 128 + slotR * 16);
            }
            #pragma unroll
            for (int m = 0; m < 4; ++m)
                #pragma unroll
                for (int n = 0; n < TNF; ++n)
                    acc[m][n] = __builtin_amdgcn_mfma_f32_16x16x32_bf16(av[m], bv[n], acc[m][n], 0, 0, 0);
        }
        __syncthreads();
        cur ^= 1;
    }

    const float* residz = (flags & F_RESID) ? resid + zsR * bz : nullptr;
    const float* biasz  = (flags & F_BIAS)  ? bias + zsBias * bz : nullptr;
    float* cfz = Cf ? Cf + zsC * bz : nullptr;
    u16*   cbz = Cb ? Cb + zsC * bz : nullptr;

    #pragma unroll
    for (int m = 0; m < 4; ++m) {
        #pragma unroll
        for (int n = 0; n < TNF; ++n) {
            int gc = bn + wc * (TNF * 16) + n * 16 + fr;
            if (gc >= Ncols) continue;
            int gr0 = bm + wr * 64 + m * 16 + fq * 4;
            #pragma unroll
            for (int r = 0; r < 4; ++r) {
                int gr = gr0 + r;
                float v = acc[m][n][r];
                if (flags & F_BIAS)  v += biasz[gc];
                if (flags & F_SILU)  v = v / (1.f + expf(-v));
                if (flags & F_RESID) v += residz[(size_t)gr * ldr + gc];
                if (flags & F_OUTBF) cbz[(size_t)gr * ldc + gc] = f2b(v);
                else                 cfz[(size_t)gr * ldc + gc] = v;
            }
        }
    }
}

// ===================== dual-job GEMM (cond + emb in one launch) =====================
struct GJob {
    const u16* A;
    const u16* BT;
    u16* C;
    const float* bias;
    int lda, ldb, ldc;
    size_t zsA, zsB, zsC, zsBias;
    int Nc, Kd, ksl, flags;
    unsigned gx, gy, start, nb;
};

__global__ __launch_bounds__(256) void gemm_dual(GJob j0, GJob j1)
{
    __shared__ u16 As[2][128 * 64];
    __shared__ u16 Bs[2][64 * 64];

    GJob J = (blockIdx.x >= j1.start) ? j1 : j0;
    unsigned bid = blockIdx.x - J.start;
    if ((J.nb & 7u) == 0u) bid = (bid & 7u) * (J.nb >> 3) + (bid >> 3);
    const int bxi = bid % J.gx;
    const int byi = (bid / J.gx) % J.gy;
    const int bz  = bid / (J.gx * J.gy);

    const int tid = threadIdx.x;
    const int l = tid & 63, w = tid >> 6;
    const int bm = byi * 128, bn = bxi * 64;

    const u16* A  = J.A + J.zsA * bz;
    const u16* BT = J.BT + J.zsB * bz;

    const int kbeg = J.ksl ? bz * J.ksl : 0;
    const int kend = J.ksl ? kbeg + J.ksl : J.Kd;
    const int nk = (kend - kbeg) >> 6;

    const int arow   = l >> 3;
    const int aslot  = l & 7;
    const int srcslt = aslot ^ arow;

    const u16* aBase[4];
    const u16* bBase[2];
    #pragma unroll
    for (int t = 0; t < 4; ++t) {
        int ra = bm + (w * 4 + t) * 8 + arow;
        aBase[t] = A + (size_t)ra * J.lda + srcslt * 8;
    }
    #pragma unroll
    for (int t = 0; t < 2; ++t) {
        int rb = bn + (w * 2 + t) * 8 + arow;
        if (rb > J.Nc - 1) rb = J.Nc - 1;
        bBase[t] = BT + (size_t)rb * J.ldb + srcslt * 8;
    }

    const int wr = w >> 1, wc = w & 1;
    const int fr = l & 15;
    const int fq = l >> 4;

    f32x4 acc[4][2];
    #pragma unroll
    for (int i = 0; i < 4; ++i)
        #pragma unroll
        for (int j = 0; j < 2; ++j) acc[i][j] = (f32x4){0.f, 0.f, 0.f, 0.f};

    auto stage = [&](int buf, int k0) {
        #pragma unroll
        for (int t = 0; t < 4; ++t)
            __builtin_amdgcn_global_load_lds((gvoid*)(aBase[t] + k0),
                (lvoid*)((char*)As[buf] + (w * 4 + t) * 1024), 16, 0, 0);
        #pragma unroll
        for (int t = 0; t < 2; ++t)
            __builtin_amdgcn_global_load_lds((gvoid*)(bBase[t] + k0),
                (lvoid*)((char*)Bs[buf] + (w * 2 + t) * 1024), 16, 0, 0);
    };

    stage(0, kbeg);
    __syncthreads();
    int cur = 0;

    for (int it = 0; it < nk; ++it) {
        if (it + 1 < nk) stage(cur ^ 1, kbeg + (it + 1) * 64);
        #pragma unroll
        for (int kk = 0; kk < 2; ++kk) {
            const int slotR = ((kk * 4) + fq) ^ (l & 7);
            short8 av[4], bv[2];
            #pragma unroll
            for (int m = 0; m < 4; ++m) {
                int r = wr * 64 + m * 16 + fr;
                av[m] = *(const short8*)((const char*)As[cur] + r * 128 + slotR * 16);
            }
            #pragma unroll
            for (int n = 0; n < 2; ++n) {
                int r = wc * 32 + n * 16 + fr;
                bv[n] = *(const short8*)((const char*)Bs[cur] + r * 128 + slotR * 16);
            }
            #pragma unroll
            for (int m = 0; m < 4; ++m)
                #pragma unroll
                for (int n = 0; n < 2; ++n)
                    acc[m][n] = __builtin_amdgcn_mfma_f32_16x16x32_bf16(av[m], bv[n], acc[m][n], 0, 0, 0);
        }
        __syncthreads();
        cur ^= 1;
    }

    const float* biasz = (J.flags & F_BIAS) ? J.bias + J.zsBias * bz : nullptr;
    u16* cbz = J.C + J.zsC * bz;

    #pragma unroll
    for (int m = 0; m < 4; ++m) {
        #pragma unroll
        for (int n = 0; n < 2; ++n) {
            int gc = bn + wc * 32 + n * 16 + fr;
            if (gc >= J.Nc) continue;
            int gr0 = bm + wr * 64 + m * 16 + fq * 4;
            #pragma unroll
            for (int r = 0; r < 4; ++r) {
                int gr = gr0 + r;
                float v = acc[m][n][r];
                if (J.flags & F_BIAS) v += biasz[gc];
                cbz[(size_t)gr * J.ldc + gc] = f2b(v);
            }
        }
    }
}

// ===================== split-K reduce (bf16 partials) + fused epilogue ==========
__global__ __launch_bounds__(256) void reduce_epi(
    const u16* __restrict__ part, size_t slice, int nsl,
    float* __restrict__ Cf, u16* __restrict__ Cb,
    const float* __restrict__ bias,
    const float* __restrict__ resid, int ldr,
    int M, int Ncols, int flags)
{
    if ((Ncols & 7) == 0) {
        size_t total8 = (size_t)M * Ncols / 8;
        for (size_t i8 = (size_t)blockIdx.x * 256 + threadIdx.x; i8 < total8;
             i8 += (size_t)gridDim.x * 256) {
            size_t i0 = i8 * 8;
            int r = (int)(i0 / (unsigned)Ncols);
            int c0 = (int)(i0 - (size_t)r * Ncols);
            float v[8] = {0,0,0,0,0,0,0,0};
            for (int s = 0; s < nsl; ++s) {
                const u16x4* p = (const u16x4*)(part + (size_t)s * slice + i0);
                u16x4 a = p[0], b = p[1];
                v[0] += b2f(a.x); v[1] += b2f(a.y); v[2] += b2f(a.z); v[3] += b2f(a.w);
                v[4] += b2f(b.x); v[5] += b2f(b.y); v[6] += b2f(b.z); v[7] += b2f(b.w);
            }
            #pragma unroll
            for (int j = 0; j < 8; ++j) {
                if (flags & F_BIAS) v[j] += bias[c0 + j];
                if (flags & F_SILU) v[j] = v[j] / (1.f + expf(-v[j]));
            }
            if (flags & F_RESID) {
                const float4* rp = (const float4*)(resid + (size_t)r * ldr + c0);
                float4 r0 = rp[0], r1 = rp[1];
                v[0] += r0.x; v[1] += r0.y; v[2] += r0.z; v[3] += r0.w;
                v[4] += r1.x; v[5] += r1.y; v[6] += r1.z; v[7] += r1.w;
            }
            if (flags & F_OUTBF) {
                short8 o;
                #pragma unroll
                for (int j = 0; j < 8; ++j) o[j] = (short)f2b(v[j]);
                *(short8*)(Cb + i0) = o;
            } else {
                float4 o0 = {v[0], v[1], v[2], v[3]}, o1 = {v[4], v[5], v[6], v[7]};
                float4* cp = (float4*)(Cf + i0);
                cp[0] = o0; cp[1] = o1;
            }
        }
    } else {
        size_t total = (size_t)M * Ncols;
        for (size_t i = (size_t)blockIdx.x * 256 + threadIdx.x; i < total;
             i += (size_t)gridDim.x * 256) {
            float v = 0.f;
            for (int s = 0; s < nsl; ++s) v += b2f(part[(size_t)s * slice + i]);
            if (flags & F_OUTBF) Cb[i] = f2b(v);
            else                 Cf[i] = v;
        }
    }
}

// ===== fused split-K reduce -> local update -> cond LayerNorm -> bf16 =====
__global__ __launch_bounds__(256) void reduce_cn(
    const u16* __restrict__ part, size_t slice, int nsl,
    const float* __restrict__ bias, const float* __restrict__ resid,
    float* __restrict__ locOut,
    const u16* __restrict__ cs, const u16* __restrict__ cb,
    u16* __restrict__ normB)
{
    int row = blockIdx.x, tid = threadIdx.x;
    size_t base = (size_t)row * 1024 + tid * 4;
    float v[4];
    {
        float4 rv = *(const float4*)(resid + base);
        v[0] = rv.x; v[1] = rv.y; v[2] = rv.z; v[3] = rv.w;
    }
    for (int s = 0; s < nsl; ++s) {
        u16x4 p = *(const u16x4*)(part + (size_t)s * slice + base);
        v[0] += b2f(p.x); v[1] += b2f(p.y); v[2] += b2f(p.z); v[3] += b2f(p.w);
    }
    {
        float4 bv = *(const float4*)(bias + tid * 4);
        v[0] += bv.x; v[1] += bv.y; v[2] += bv.z; v[3] += bv.w;
    }
    *(float4*)(locOut + base) = (float4){v[0], v[1], v[2], v[3]};

    float s1 = v[0] + v[1] + v[2] + v[3];
    float s2 = v[0]*v[0] + v[1]*v[1] + v[2]*v[2] + v[3]*v[3];
    __shared__ float r1[256], r2[256];
    r1[tid] = s1; r2[tid] = s2;
    __syncthreads();
    for (int st = 128; st > 0; st >>= 1) {
        if (tid < st) { r1[tid] += r1[tid + st]; r2[tid] += r2[tid + st]; }
        __syncthreads();
    }
    float mean = r1[0] * (1.f / 1024.f);
    float var = r2[0] * (1.f / 1024.f) - mean * mean;
    float rs = rsqrtf(var + 1e-5f);
    u16x4 sv = *(const u16x4*)(cs + base);
    u16x4 bv = *(const u16x4*)(cb + base);
    u16x4 o;
    o.x = f2b((1.f / (1.f + expf(-b2f(sv.x)))) * (v[0] - mean) * rs + b2f(bv.x));
    o.y = f2b((1.f / (1.f + expf(-b2f(sv.y)))) * (v[1] - mean) * rs + b2f(bv.y));
    o.z = f2b((1.f / (1.f + expf(-b2f(sv.z)))) * (v[2] - mean) * rs + b2f(bv.z));
    o.w = f2b((1.f / (1.f + expf(-b2f(sv.w)))) * (v[3] - mean) * rs + b2f(bv.w));
    *(u16x4*)(normB + base) = o;
}

// ========== fused flash attention (split-KV=4, XCD-chunked swizzle, setprio) ==========
__global__ __launch_bounds__(256, 2) void attn_kernel(
    const u16* __restrict__ qe, const u16* __restrict__ ke,
    const u16* __restrict__ vt, const float* __restrict__ pb,
    u16* __restrict__ Opart, float* __restrict__ mlpart)
{
    __shared__ u16 Ks[2][64 * 128];
    __shared__ u16 Vs[2][96 * 64];
    __shared__ u16 Ps[64 * 64];

    unsigned gx = gridDim.x, gy = gridDim.y;
    unsigned nb = gx * gy * gridDim.z;
    unsigned bid = (blockIdx.z * gy + blockIdx.y) * gx + blockIdx.x;
    bid = (bid & 7u) * (nb >> 3) + (bid >> 3);
    const int qx = bid % gx;
    const int h  = (bid / gx) % gy;
    const int z  = bid / (gx * gy);

    const int tid = threadIdx.x;
    const int l = tid & 63, w = tid >> 6;
    const int q0 = qx * 64;
    const int fr = l & 15, fq = l >> 4;

    const u16* keh = ke + (size_t)h * NRES * 128;
    const u16* vth = vt + (size_t)h * 96 * NRES;

    const int kr4 = l >> 4, ks16 = l & 15;
    const int vr8 = l >> 3, vs8 = l & 7;

    short8 qv[4];
    {
        const u16* qrow = qe + ((size_t)h * NRES + (q0 + w * 16 + fr)) * 128 + fq * 8;
        #pragma unroll
        for (int kk = 0; kk < 4; ++kk)
            qv[kk] = *(const short8*)(qrow + kk * 32);
    }

    float m_run[4], l_run[4];
    f32x4 oacc[6];
    #pragma unroll
    for (int r = 0; r < 4; ++r) { m_run[r] = -1e30f; l_run[r] = 0.f; }
    #pragma unroll
    for (int n = 0; n < 6; ++n) oacc[n] = (f32x4){0.f, 0.f, 0.f, 0.f};

    const int NIT = NRES / 64 / KVS;
    const int jbase = z * (NRES / KVS);
    int cur = 0;

    auto stage = [&](int buf, int j0) {
        #pragma unroll
        for (int t = 0; t < 4; ++t) {
            int row = w * 16 + t * 4 + kr4;
            int ss = ks16 ^ (row & 7);
            __builtin_amdgcn_global_load_lds(
                (gvoid*)(keh + (size_t)(j0 + row) * 128 + ss * 8),
                (lvoid*)((char*)Ks[buf] + (w * 16 + t * 4) * 256), 16, 0, 0);
        }
        #pragma unroll
        for (int t = 0; t < 3; ++t) {
            int row = w * 24 + t * 8 + vr8;
            int ss = vs8 ^ (row & 7);
            __builtin_amdgcn_global_load_lds(
                (gvoid*)(vth + (size_t)row * NRES + j0 + ss * 8),
                (lvoid*)((char*)Vs[buf] + (w * 24 + t * 8) * 128), 16, 0, 0);
        }
    };
    const float* pbrow = pb + ((size_t)h * NRES + (q0 + w * 16 + fq * 4)) * NRES + fr;

    f32x4 pbv[4], pbn[4] = {};
    stage(0, jbase);
    #pragma unroll
    for (int n = 0; n < 4; ++n)
        #pragma unroll
        for (int r = 0; r < 4; ++r)
            pbv[n][r] = pbrow[(size_t)r * NRES + jbase + n * 16];
    __syncthreads();

    for (int it = 0; it < NIT; ++it) {
        if (it + 1 < NIT) {
            int j1 = jbase + (it + 1) * 64;
            stage(cur ^ 1, j1);
            #pragma unroll
            for (int n = 0; n < 4; ++n)
                #pragma unroll
                for (int r = 0; r < 4; ++r)
                    pbn[n][r] = pbrow[(size_t)r * NRES + j1 + n * 16];
        }

        f32x4 sacc[4];
        #pragma unroll
        for (int n = 0; n < 4; ++n) sacc[n] = (f32x4){0.f, 0.f, 0.f, 0.f};
        __builtin_amdgcn_s_setprio(1);
        #pragma unroll
        for (int kk = 0; kk < 4; ++kk) {
            #pragma unroll
            for (int n = 0; n < 4; ++n) {
                int row = n * 16 + fr;
                short8 bv = *(const short8*)((const char*)Ks[cur] + row * 256
                                             + (((kk * 4 + fq) ^ (fr & 7)) * 16));
                sacc[n] = __builtin_amdgcn_mfma_f32_16x16x32_bf16(qv[kk], bv, sacc[n], 0, 0, 0);
            }
        }
        __builtin_amdgcn_s_setprio(0);
        #pragma unroll
        for (int n = 0; n < 4; ++n) sacc[n] += pbv[n];

        float alpha[4];
        #pragma unroll
        for (int r = 0; r < 4; ++r) {
            float v = fmaxf(fmaxf(sacc[0][r], sacc[1][r]), fmaxf(sacc[2][r], sacc[3][r]));
            v = fmaxf(v, __shfl_xor(v, 1, 64));
            v = fmaxf(v, __shfl_xor(v, 2, 64));
            v = fmaxf(v, __shfl_xor(v, 4, 64));
            v = fmaxf(v, __shfl_xor(v, 8, 64));
            float mn = fmaxf(m_run[r], v);
            alpha[r] = exp2f((m_run[r] - mn) * LOG2E);
            m_run[r] = mn;
        }

        float psum[4] = {0.f, 0.f, 0.f, 0.f};
        #pragma unroll
        for (int n = 0; n < 4; ++n) {
            int col = n * 16 + fr;
            #pragma unroll
            for (int r = 0; r < 4; ++r) {
                float p = exp2f((sacc[n][r] - m_run[r]) * LOG2E);
                psum[r] += p;
                int rowf = w * 16 + fq * 4 + r;
                int byte = rowf * 128 + (((col >> 3) ^ (rowf & 7)) * 16) + (col & 7) * 2;
                *(u16*)((char*)Ps + byte) = f2b(p);
            }
        }
        #pragma unroll
        for (int r = 0; r < 4; ++r) {
            float v = psum[r];
            v += __shfl_xor(v, 1, 64);
            v += __shfl_xor(v, 2, 64);
            v += __shfl_xor(v, 4, 64);
            v += __shfl_xor(v, 8, 64);
            l_run[r] = l_run[r] * alpha[r] + v;
        }
        #pragma unroll
        for (int n = 0; n < 6; ++n)
            #pragma unroll
            for (int r = 0; r < 4; ++r)
                oacc[n][r] *= alpha[r];

        __builtin_amdgcn_s_setprio(1);
        #pragma unroll
        for (int kk = 0; kk < 2; ++kk) {
            int prow = w * 16 + fr;
            short8 pa = *(const short8*)((const char*)Ps + prow * 128
                                         + (((kk * 4 + fq) ^ (prow & 7)) * 16));
            #pragma unroll
            for (int n = 0; n < 6; ++n) {
                int vrow = n * 16 + fr;
                short8 vv = *(const short8*)((const char*)Vs[cur] + vrow * 128
                                             + (((kk * 4 + fq) ^ (fr & 7)) * 16));
                oacc[n] = __builtin_amdgcn_mfma_f32_16x16x32_bf16(pa, vv, oacc[n], 0, 0, 0);
            }
        }
        __builtin_amdgcn_s_setprio(0);

        __syncthreads();
        cur ^= 1;
        #pragma unroll
        for (int n = 0; n < 4; ++n) pbv[n] = pbn[n];
    }

    u16* Oz = Opart + ((size_t)z * NH + h) * NRES * 96;
    #pragma unroll
    for (int n = 0; n < 6; ++n) {
        int c = n * 16 + fr;
        #pragma unroll
        for (int r = 0; r < 4; ++r) {
            int row = q0 + w * 16 + fq * 4 + r;
            Oz[(size_t)row * 96 + c] = f2b(oacc[n][r]);
        }
    }
    if (fr == 0) {
        float* mlz = mlpart + ((size_t)z * NH + h) * NRES * 2;
        #pragma unroll
        for (int r = 0; r < 4; ++r) {
            int row = q0 + w * 16 + fq * 4 + r;
            mlz[row * 2 + 0] = m_run[r];
            mlz[row * 2 + 1] = l_run[r];
        }
    }
}

// ========== fused combine(split-KV) + finalize -> featB ==========
__global__ __launch_bounds__(256) void combine_fin(
    const u16* __restrict__ Opart, const float* __restrict__ mlpart,
    const float* __restrict__ Rb, const float* __restrict__ tb,
    u16* __restrict__ featB)
{
    int idx = blockIdx.x * 256 + threadIdx.x;
    if (idx >= NRES * NH) return;
    int n = idx >> 4, h = idx & 15;

    float m[KVS], lv[KVS], wgt[KVS];
    float mm = -1e30f;
    #pragma unroll
    for (int s = 0; s < KVS; ++s) {
        size_t rr = ((size_t)s * NH + h) * NRES + n;
        m[s] = mlpart[rr * 2];
        lv[s] = mlpart[rr * 2 + 1];
        mm = fmaxf(mm, m[s]);
    }
    float ll = 0.f;
    #pragma unroll
    for (int s = 0; s < KVS; ++s) {
        wgt[s] = exp2f((m[s] - mm) * LOG2E);
        ll += lv[s] * wgt[s];
    }
    float inv = 1.f / ll;
    const u16* op[KVS];
    #pragma unroll
    for (int s = 0; s < KVS; ++s)
        op[s] = Opart + (((size_t)s * NH + h) * NRES + n) * 96;

    u16* fb = featB + (size_t)n * 1536;
    #pragma unroll
    for (int k = 0; k < 64; ++k) {
        float v = 0.f;
        #pragma unroll
        for (int s = 0; s < KVS; ++s) v += b2f(op[s][k]) * wgt[s];
        fb[h * 64 + k] = f2b(v * inv);
    }

    float R[9];
    #pragma unroll
    for (int a = 0; a < 9; ++a) R[a] = Rb[(size_t)n * 9 + a];
    float t0 = tb[(size_t)n * 3 + 0], t1 = tb[(size_t)n * 3 + 1], t2 = tb[(size_t)n * 3 + 2];
    #pragma unroll
    for (int p = 0; p < 8; ++p) {
        float d[3];
        #pragma unroll
        for (int dd = 0; dd < 3; ++dd) {
            int c = 64 + p * 3 + dd;
            float v = 0.f;
            #pragma unroll
            for (int s = 0; s < KVS; ++s) v += b2f(op[s][c]) * wgt[s];
            d[dd] = v * inv;
        }
        float x = d[0] - t0, y = d[1] - t1, z = d[2] - t2;
        float a0 = R[0] * x + R[3] * y + R[6] * z;
        float a1 = R[1] * x + R[4] * y + R[7] * z;
        float a2 = R[2] * x + R[5] * y + R[8] * z;
        fb[1024 + h * 24 + p * 3 + 0] = f2b(a0);
        fb[1024 + h * 24 + p * 3 + 1] = f2b(a1);
        fb[1024 + h * 24 + p * 3 + 2] = f2b(a2);
        fb[1408 + h * 8 + p] = f2b(sqrtf(a0 * a0 + a1 * a1 + a2 * a2 + 1e-8f));
    }
}

// ============ prep: prologue + ALL weight transposes in ONE launch ============
struct TpMega {
    const float* src[NTPJ];
    u16* dst[NTPJ];
    int ldi[NTPJ], ldo[NTPJ], K[NTPJ], N[NTPJ];
    int bx[NTPJ], start[NTPJ];
};

__global__ __launch_bounds__(256) void prep_kernel(
    const float* __restrict__ pos, const float* __restrict__ cond,
    const float* __restrict__ cn1_bs, const float* __restrict__ cn1_bb,
    const float* __restrict__ cn2_bs, const float* __restrict__ cn2_bb,
    const float* __restrict__ cn3_bs, const float* __restrict__ cn3_bb,
    const float* __restrict__ bg1, const float* __restrict__ bg2,
    float* __restrict__ Rb, float* __restrict__ tb,
    u16* __restrict__ emb, u16* __restrict__ condB,
    float* __restrict__ bias2, float* __restrict__ biasg,
    TpMega J)
{
    __shared__ float t[32][33];
    int b = blockIdx.x, tid = threadIdx.x;
    if (b >= PROBLK) {
        int tb2 = b - PROBLK;
        int j = NTPJ - 1;
        while (J.start[j] > tb2) --j;
        int lb = tb2 - J.start[j];
        int bxn = J.bx[j];
        int n0 = (lb % bxn) * 32;
        int k0 = (lb / bxn) * 32;
        const float* in = J.src[j];
        u16* out = J.dst[j];
        int ldi = J.ldi[j], ldo = J.ldo[j], Kk = J.K[j], Nn = J.N[j];
        int tx = tid & 31, ty = tid >> 5;
        #pragma unroll
        for (int jj = 0; jj < 4; ++jj) {
            int k = k0 + ty + jj * 8;
            if (k < Kk && n0 + tx < Nn) t[ty + jj * 8][tx] = in[(size_t)k * ldi + n0 + tx];
        }
        __syncthreads();
        #pragma unroll
        for (int jj = 0; jj < 4; ++jj) {
            int n = n0 + ty + jj * 8;
            int k = k0 + tx;
            if (n < Nn && k < Kk) out[(size_t)n * ldo + k] = f2b(t[tx][ty + jj * 8]);
        }
        return;
    }
    if (b < 16128) {
        int idx = b * 256 + tid;
        int f = idx & 63;
        int rest = idx >> 6;
        int coord = rest % 42;
        int n = rest / 42;
        float tt = pos[(size_t)n * 42 + coord];
        const double l0 = -6.643856189774724;
        const double step = 14.643856189774724 / 63.0;
        float freq = exp2f((float)(l0 + f * step));
        float r = tt * freq;
        size_t o = (size_t)n * 5376 + (size_t)coord * 128 + 2 * f;
        emb[o]     = f2b(sinf(r));
        emb[o + 1] = f2b(cosf(r));
    } else if (b < 16896) {
        int i = (b - 16128) * 256 + tid;
        size_t i0 = (size_t)i * 8;
        const float4* p = (const float4*)(cond + i0);
        float4 a = p[0], bb = p[1];
        short8 o;
        o[0]=(short)f2b(a.x); o[1]=(short)f2b(a.y); o[2]=(short)f2b(a.z); o[3]=(short)f2b(a.w);
        o[4]=(short)f2b(bb.x); o[5]=(short)f2b(bb.y); o[6]=(short)f2b(bb.z); o[7]=(short)f2b(bb.w);
        *(short8*)(condB + i0) = o;
    } else if (b < 16902) {
        int n = (b - 16896) * 256 + tid;
        if (n >= NRES) return;
        const float* p = pos + (size_t)n * 42;
        float nx = p[0], ny = p[1], nz = p[2];
        float cax = p[3], cay = p[4], caz = p[5];
        float cx = p[6], cy = p[7], cz = p[8];
        float v1x = cx - cax, v1y = cy - cay, v1z = cz - caz;
        float i1 = rsqrtf(v1x * v1x + v1y * v1y + v1z * v1z + 1e-8f);
        float e1x = v1x * i1, e1y = v1y * i1, e1z = v1z * i1;
        float v2x = nx - cax, v2y = ny - cay, v2z = nz - caz;
        float d = e1x * v2x + e1y * v2y + e1z * v2z;
        float wx = v2x - d * e1x, wy = v2y - d * e1y, wz = v2z - d * e1z;
        float i2 = rsqrtf(wx * wx + wy * wy + wz * wz + 1e-8f);
        float e2x = wx * i2, e2y = wy * i2, e2z = wz * i2;
        float e3x = e1y * e2z - e1z * e2y;
        float e3y = e1z * e2x - e1x * e2z;
        float e3z = e1x * e2y - e1y * e2x;
        float* R = Rb + (size_t)n * 9;
        R[0] = e1x; R[1] = e2x; R[2] = e3x;
        R[3] = e1y; R[4] = e2y; R[5] = e3y;
        R[6] = e1z; R[7] = e2z; R[8] = e3z;
        tb[(size_t)n * 3 + 0] = cax;
        tb[(size_t)n * 3 + 1] = cay;
        tb[(size_t)n * 3 + 2] = caz;
    } else if (b < 16906) {
        int i = (b - 16902) * 256 + tid;
        if (i >= 1024) return;
        bias2[i] = cn1_bs[i]; bias2[1024 + i] = cn1_bb[i]; bias2[2048 + i] = cn2_bs[i];
        bias2[3072 + i] = cn2_bb[i]; bias2[4096 + i] = cn3_bs[i]; bias2[5120 + i] = cn3_bb[i];
    } else {
        int i = (b - 16906) * 256 + tid;
        if (i >= 2048) return;
        biasg[i] = bg1[i]; biasg[2048 + i] = bg2[i];
    }
}

// ===== pack_all: qk pack + qe/ke points + vT transpose (vgt eliminated) ============
// blocks [0,1536): qk cols; [1536,1632): q/k points; [1632,1632+2304): vT pack.
__global__ __launch_bounds__(256) void pack_all(
    const u16* __restrict__ qkc,
    const float* __restrict__ Rb, const float* __restrict__ tb,
    const float* __restrict__ gamma,
    u16* __restrict__ qe, u16* __restrict__ ke, u16* __restrict__ vt)
{
    int b = blockIdx.x;
    if (b < 1536) {
        int idx = b * 256 + threadIdx.x;
        int g = idx & 15;
        int t = idx >> 4;
        int n = t % NRES;
        int h = t / NRES;
        size_t o = ((size_t)h * NRES + n) * 128 + g * 8;
        if (g < 8) {
            short8 q8 = *(const short8*)(qkc + (size_t)n * LDQ + h * 64 + g * 8);
            short8 k8 = *(const short8*)(qkc + (size_t)n * LDQ + 1024 + h * 64 + g * 8);
            short8 oq;
            #pragma unroll
            for (int j = 0; j < 8; ++j) oq[j] = (short)f2b(0.125f * b2f((u16)q8[j]));
            *(short8*)(qe + o) = oq;
            *(short8*)(ke + o) = k8;
        } else if (g >= 11) {
            short8 zz = {};
            *(short8*)(qe + o) = zz;
            *(short8*)(ke + o) = zz;
        }
        return;
    }
    if (b < 1632) {
        int idx = (b - 1536) * 256 + threadIdx.x;
        if (idx >= NRES * NH) return;
        int n = idx >> 4, h = idx & 15;
        float R[9];
        #pragma unroll
        for (int a = 0; a < 9; ++a) R[a] = Rb[(size_t)n * 9 + a];
        float t0 = tb[(size_t)n * 3 + 0], t1 = tb[(size_t)n * 3 + 1], t2 = tb[(size_t)n * 3 + 2];
        float g = gamma[h];
        float sp = (g > 20.f) ? g : log1pf(expf(g));
        float ch = 0.5f * (1.f / 6.f) * sp;

        u16* qeh = qe + ((size_t)h * NRES + n) * 128;
        u16* keh = ke + ((size_t)h * NRES + n) * 128;
        const u16* qp = qkc + (size_t)n * LDQ + 3072 + h * 24;
        const u16* kp = qkc + (size_t)n * LDQ + 3456 + h * 24;
        float kn = 0.f;
        #pragma unroll
        for (int p = 0; p < 8; ++p) {
            {
                float x = b2f(qp[p*3]), y = b2f(qp[p*3+1]), z = b2f(qp[p*3+2]);
                float g0 = R[0] * x + R[1] * y + R[2] * z + t0;
                float g1 = R[3] * x + R[4] * y + R[5] * z + t1;
                float g2 = R[6] * x + R[7] * y + R[8] * z + t2;
                qeh[64 + p * 3 + 0] = f2b(2.f * ch * g0);
                qeh[64 + p * 3 + 1] = f2b(2.f * ch * g1);
                qeh[64 + p * 3 + 2] = f2b(2.f * ch * g2);
            }
            {
                float x = b2f(kp[p*3]), y = b2f(kp[p*3+1]), z = b2f(kp[p*3+2]);
                float g0 = R[0] * x + R[1] * y + R[2] * z + t0;
                float g1 = R[3] * x + R[4] * y + R[5] * z + t1;
                float g2 = R[6] * x + R[7] * y + R[8] * z + t2;
                keh[64 + p * 3 + 0] = f2b(g0);
                keh[64 + p * 3 + 1] = f2b(g1);
                keh[64 + p * 3 + 2] = f2b(g2);
                kn += g0 * g0 + g1 * g1 + g2 * g2;
            }
        }
        qeh[88] = f2b(1.0f);
        keh[88] = f2b(-ch * kn);
        return;
    }
    // ---- vT pack: lb decomposed as (h, grp, n-block); V rotation computed inline ----
    __shared__ float t[32][33];
    int lb = b - 1632;
    int h = lb / 144;              // 48*3 = 144 blocks per head
    int rem = lb - h * 144;
    int grp = rem / 48;
    int n0 = (rem - grp * 48) * 32;
    int tx = threadIdx.x & 31, ty = threadIdx.x >> 5;
    #pragma unroll
    for (int j = 0; j < 4; ++j) {
        int n = n0 + ty + j * 8;
        int c = grp * 32 + tx;
        float v = 0.f;
        if (c < 64) {
            v = b2f(qkc[(size_t)n * LDQ + 2048 + h * 64 + c]);
        } else if (c < 88) {
            int pc = c - 64;
            int p = pc / 3, a = pc - p * 3;
            const u16* vp = qkc + (size_t)n * LDQ + 3840 + h * 24 + p * 3;
            float x = b2f(vp[0]), y = b2f(vp[1]), z = b2f(vp[2]);
            v = Rb[(size_t)n * 9 + 3 * a + 0] * x + Rb[(size_t)n * 9 + 3 * a + 1] * y
              + Rb[(size_t)n * 9 + 3 * a + 2] * z + tb[(size_t)n * 3 + a];
        }
        t[ty + j * 8][tx] = v;
    }
    __syncthreads();
    #pragma unroll
    for (int j = 0; j < 4; ++j) {
        int r = grp * 32 + ty + j * 8;
        vt[((size_t)h * 96 + r) * NRES + n0 + tx] = f2b(t[tx][ty + j * 8]);
    }
}

// gm = silu(g1) * g2, 8-wide
__global__ __launch_bounds__(256) void glu_kernel(const u16* __restrict__ g12, u16* __restrict__ gm)
{
    int i = blockIdx.x * 256 + threadIdx.x;
    if (i >= NRES * 2048 / 8) return;
    size_t i0 = (size_t)i * 8;
    short8 a8 = *(const short8*)(g12 + i0);
    short8 b8 = *(const short8*)(g12 + (size_t)NRES * 2048 + i0);
    short8 o;
    #pragma unroll
    for (int j = 0; j < 8; ++j) {
        float a = b2f((u16)a8[j]);
        float b = b2f((u16)b8[j]);
        float s = a / (1.f + expf(-a));
        o[j] = (short)f2b(s * b);
    }
    *(short8*)(gm + i0) = o;
}

// ========================= host =========================
extern "C" void kernel_launch(void* const* d_in, const int* in_sizes, int n_in,
                              void* d_out, int out_size, void* d_ws, size_t ws_size,
                              hipStream_t stream)
{
    const float* local_in = (const float*)d_in[0];
    const float* pos      = (const float*)d_in[1];
    const float* cond     = (const float*)d_in[2];
    const float* pb       = (const float*)d_in[4];
    const float* w_f1     = (const float*)d_in[5];
    const float* b_f1     = (const float*)d_in[6];
    const float* w_f2     = (const float*)d_in[7];
    const float* b_f2     = (const float*)d_in[8];
    const float* cn1_ws   = (const float*)d_in[9];
    const float* cn1_bs   = (const float*)d_in[10];
    const float* cn1_wb   = (const float*)d_in[11];
    const float* cn1_bb   = (const float*)d_in[12];
    const float* wq       = (const float*)d_in[13];
    const float* wk       = (const float*)d_in[14];
    const float* wv       = (const float*)d_in[15];
    const float* wqp      = (const float*)d_in[16];
    const float* wkp      = (const float*)d_in[17];
    const float* wvp      = (const float*)d_in[18];
    const float* gamma    = (const float*)d_in[19];
    const float* wo       = (const float*)d_in[20];
    const float* bo       = (const float*)d_in[21];
    const float* cn2_ws   = (const float*)d_in[22];
    const float* cn2_bs   = (const float*)d_in[23];
    const float* cn2_wb   = (const float*)d_in[24];
    const float* cn2_bb   = (const float*)d_in[25];
    const float* wg1      = (const float*)d_in[26];
    const float* bg1      = (const float*)d_in[27];
    const float* wg2      = (const float*)d_in[28];
    const float* bg2      = (const float*)d_in[29];
    const float* wg3      = (const float*)d_in[30];
    const float* bg3      = (const float*)d_in[31];
    const float* cn3_ws   = (const float*)d_in[32];
    const float* cn3_bs   = (const float*)d_in[33];
    const float* cn3_wb   = (const float*)d_in[34];
    const float* cn3_bb   = (const float*)d_in[35];
    const float* w_vel    = (const float*)d_in[36];

    float* out = (float*)d_out;
    float* ws  = (float*)d_ws;

    size_t off = 0;
    auto alloc = [&](size_t nf) -> float* { float* p = ws + off; off += (nf + 7) & ~7ull; return p; };

    const size_t NN1 = (size_t)NRES * 1024;
    float* Rb    = alloc(NRES * 9);
    float* tb    = alloc(NRES * 3);
    float* loc   = alloc(NN1);
    u16*   cs6b  = (u16*)alloc(6 * NN1 / 2);
    u16*   condB = (u16*)alloc(NN1 / 2);
    u16*   normB = (u16*)alloc(NN1 / 2);
    float* bias2 = alloc(6 * 1024);
    float* biasg = alloc(2 * 2048);
    u16*   qkcB  = (u16*)alloc((size_t)NRES * LDQ / 2);
    u16*   qeB   = (u16*)alloc((size_t)NH * NRES * 128 / 2);
    u16*   keB   = (u16*)alloc((size_t)NH * NRES * 128 / 2);
    u16*   vTB   = (u16*)alloc((size_t)NH * 96 * NRES / 2);
    u16*   featB = (u16*)alloc((size_t)NRES * 1536 / 2);
    u16*   g1sB  = (u16*)alloc((size_t)NRES * 2048 / 2);
    u16*   gmB   = (u16*)alloc((size_t)NRES * 2048 / 2);
    u16*   cnT9  = (u16*)alloc((size_t)9 * 1024 * 1024 / 2);
    u16*   ptsT  = (u16*)alloc((size_t)3 * 384 * 1024 / 2);
    u16*   wgT   = (u16*)alloc((size_t)2 * 2048 * 1024 / 2);
    u16*   wf1T  = (u16*)alloc((size_t)2048 * 5376 / 2);
    u16*   wf2T  = (u16*)alloc((size_t)1024 * 2048 / 2);
    u16*   woT   = (u16*)alloc((size_t)1024 * 1536 / 2);
    u16*   wg3T  = (u16*)alloc((size_t)1024 * 2048 / 2);
    u16*   wvT   = (u16*)alloc((size_t)42 * 1024 / 2 + 8);
    u16*   embB  = (u16*)alloc((size_t)NRES * 5376 / 2);
    u16*   hidB  = (u16*)alloc((size_t)NRES * 2048 / 2);
    u16*   pscr  = (u16*)alloc((size_t)2 * NRES * 2048 * 4 / 2);
    u16*   Opart = (u16*)alloc((size_t)KVS * NH * NRES * 96 / 2);
    float* mlprt = alloc((size_t)KVS * NH * NRES * 2);

    const float* nilf = nullptr;

    auto gemm = [&](int tnf, const u16* A, int lda, size_t zsA,
                    const u16* BT, int ldb, size_t zsB,
                    float* Cf, u16* Cb2, int ldc, size_t zsC,
                    const float* bias, size_t zsBias,
                    const float* resid, int ldr, size_t zsR,
                    int Nc, int Kd, int flags, int gz, int ksl) {
        int tn = tnf * 32;
        dim3 grid((Nc + tn - 1) / tn, NRES / 128, gz);
        if (tnf == 4)
            hipLaunchKernelGGL(gemm_t<4>, grid, dim3(256), 0, stream,
                               A, lda, zsA, BT, ldb, zsB, Cf, Cb2, ldc, zsC,
                               bias, zsBias, resid, ldr, zsR, Nc, Kd, flags, ksl);
        else
            hipLaunchKernelGGL(gemm_t<2>, grid, dim3(256), 0, stream,
                               A, lda, zsA, BT, ldb, zsB, Cf, Cb2, ldc, zsC,
                               bias, zsBias, resid, ldr, zsR, Nc, Kd, flags, ksl);
    };
    auto red = [&](const u16* part, size_t slice, int nsl, float* Cf, u16* Cb2,
                   const float* bias, const float* resid, int ldr, int Nc, int flags) {
        hipLaunchKernelGGL(reduce_epi, dim3(1024), dim3(256), 0, stream,
                           part, slice, nsl, Cf, Cb2, bias, resid, ldr, NRES, Nc, flags);
    };
    auto redcn = [&](const u16* part, size_t slice, int nsl,
                     const float* bias, const float* resid, float* locOut, int cnIdx) {
        hipLaunchKernelGGL(reduce_cn, dim3(NRES), dim3(256), 0, stream,
                           part, slice, nsl, bias, resid, locOut,
                           cs6b + (size_t)(2 * cnIdx) * NN1,
                           cs6b + (size_t)(2 * cnIdx + 1) * NN1, normB);
    };

    // ---- prep: prologue + all weight transposes in ONE launch ----
    {
        TpMega J;
        int jn = 0, start = 0;
        auto addJob = [&](const float* src, u16* dst, int ldi, int ldo, int K, int N) {
            J.src[jn] = src; J.dst[jn] = dst;
            J.ldi[jn] = ldi; J.ldo[jn] = ldo; J.K[jn] = K; J.N[jn] = N;
            int bx = (N + 31) / 32, by = (K + 31) / 32;
            J.bx[jn] = bx; J.start[jn] = start;
            start += bx * by;
            ++jn;
        };
        const float* cn6[6] = {cn1_ws, cn1_wb, cn2_ws, cn2_wb, cn3_ws, cn3_wb};
        for (int i = 0; i < 6; ++i)
            addJob(cn6[i], cnT9 + (size_t)i * 1024 * 1024, 1024, 1024, 1024, 1024);
        addJob(wq, cnT9 + (size_t)6 * 1024 * 1024, 1024, 1024, 1024, 1024);
        addJob(wk, cnT9 + (size_t)7 * 1024 * 1024, 1024, 1024, 1024, 1024);
        addJob(wv, cnT9 + (size_t)8 * 1024 * 1024, 1024, 1024, 1024, 1024);
        addJob(wqp, ptsT,                        384, 1024, 1024, 384);
        addJob(wkp, ptsT + (size_t)384 * 1024,   384, 1024, 1024, 384);
        addJob(wvp, ptsT + (size_t)2 * 384 * 1024, 384, 1024, 1024, 384);
        addJob(wg1, wgT,                        2048, 1024, 1024, 2048);
        addJob(wg2, wgT + (size_t)2048 * 1024,  2048, 1024, 1024, 2048);
        addJob(w_f1, wf1T, 2048, 5376, 5376, 2048);
        addJob(w_f2, wf2T, 1024, 2048, 2048, 1024);
        addJob(wo,   woT,  1024, 1536, 1536, 1024);
        addJob(wg3,  wg3T, 1024, 2048, 2048, 1024);
        addJob(w_vel, wvT,   42, 1024, 1024, 42);
        hipLaunchKernelGGL(prep_kernel, dim3(PROBLK + start), dim3(256), 0, stream,
                           pos, cond, cn1_bs, cn1_bb, cn2_bs, cn2_bb, cn3_bs, cn3_bb,
                           bg1, bg2, Rb, tb, embB, condB, bias2, biasg, J);
    }

    // ---- cond (z=6) + emb (split-K=4) GEMMs fused in ONE launch ----
    {
        GJob jc, je;
        jc.A = condB; jc.BT = cnT9; jc.C = cs6b; jc.bias = bias2;
        jc.lda = 1024; jc.ldb = 1024; jc.ldc = 1024;
        jc.zsA = 0; jc.zsB = (size_t)1024 * 1024; jc.zsC = NN1; jc.zsBias = 1024;
        jc.Nc = 1024; jc.Kd = 1024; jc.ksl = 0; jc.flags = F_BIAS;
        jc.gx = 16; jc.gy = 12; jc.start = 0; jc.nb = 16 * 12 * 6;
        je.A = embB; je.BT = wf1T; je.C = pscr; je.bias = nullptr;
        je.lda = 5376; je.ldb = 5376; je.ldc = 2048;
        je.zsA = 0; je.zsB = 0; je.zsC = (size_t)NRES * 2048; je.zsBias = 0;
        je.Nc = 2048; je.Kd = 5376; je.ksl = 1344; je.flags = 0;
        je.gx = 32; je.gy = 12; je.start = jc.nb; je.nb = 32 * 12 * 4;
        hipLaunchKernelGGL(gemm_dual, dim3(jc.nb + je.nb), dim3(256), 0, stream, jc, je);
    }
    red(pscr, (size_t)NRES * 2048, 4, nullptr, hidB, b_f1, nilf, 0,
        2048, F_BIAS | F_SILU | F_OUTBF);
    gemm(2, hidB, 2048, 0, wf2T, 2048, 0, nullptr, pscr, 1024, NN1,
         nilf, 0, nilf, 0, 0, 1024, 2048, F_OUTBF, 4, 512);
    redcn(pscr, NN1, 4, b_f2, local_in, loc, 0);

    // ---- merged projections -> qkc bf16 ----
    gemm(2, normB, 1024, 0, cnT9 + (size_t)6 * 1024 * 1024, 1024, 0,
         nullptr, qkcB, LDQ, 0, nilf, 0, nilf, 0, 0, LDQ, 1024, F_OUTBF, 1, 0);

    // ---- attention operands (ONE launch: qk pack + points + vT) ----
    hipLaunchKernelGGL(pack_all, dim3(1632 + 2304), dim3(256), 0, stream,
                       qkcB, Rb, tb, gamma, qeB, keB, vTB);

    // ---- fused attention (split-KV=4, XCD-chunked) + merged combine+finalize ----
    hipLaunchKernelGGL(attn_kernel, dim3(NRES / 64, NH, KVS), dim3(256), 0, stream,
                       qeB, keB, vTB, pb, Opart, mlprt);
    hipLaunchKernelGGL(combine_fin, dim3(96), dim3(256), 0, stream,
                       Opart, mlprt, Rb, tb, featB);

    // ---- local += feat @ wo + bo : split-K=4, fused reduce+condnorm2 ----
    gemm(2, featB, 1536, 0, woT, 1536, 0, nullptr, pscr, 1024, NN1,
         nilf, 0, nilf, 0, 0, 1024, 1536, F_OUTBF, 4, 384);
    redcn(pscr, NN1, 4, bo, loc, loc, 1);

    // ---- gated MLP ----
    gemm(2, normB, 1024, 0, wgT, 1024, (size_t)2048 * 1024, nullptr, g1sB, 2048, (size_t)NRES * 2048,
         biasg, 2048, nilf, 0, 0, 2048, 1024, F_BIAS | F_OUTBF, 2, 0);
    u16* gmO = embB;
    hipLaunchKernelGGL(glu_kernel, dim3((NRES * 2048 / 8 + 255) / 256), dim3(256), 0, stream, g1sB, gmO);
    gemm(2, gmO, 2048, 0, wg3T, 2048, 0, nullptr, pscr, 1024, NN1,
         nilf, 0, nilf, 0, 0, 1024, 2048, F_OUTBF, 4, 512);
    redcn(pscr, NN1, 4, bg3, loc, out, 2);

    // ---- velocity (split-K=8, bf16 partials) ----
    gemm(2, normB, 1024, 0, wvT, 1024, 0, nullptr, pscr, 42, (size_t)NRES * 42,
         nilf, 0, nilf, 0, 0, 42, 1024, F_OUTBF, 8, 128);
    red(pscr, (size_t)NRES * 42, 8, out + (size_t)NRES * 1024, nullptr,
        nilf, nilf, 0, 42, 0);
}